// Round 6
// baseline (1164.833 us; speedup 1.0000x reference)
//
#include <hip/hip_runtime.h>
#include <math.h>

// No automatic FMA contraction anywhere: numpy-emulation arithmetic
// (square-then-add, sub-then-add) must round exactly like the reference.
// Explicit fmaf() stays fused regardless.
#pragma clang fp contract(off)

#define N_ROWS 32768
#define DIM    256
#define K_EMB  8192
#define CAP    24
#define BCAP   4096

typedef float  f32x4  __attribute__((ext_vector_type(4)));
typedef short  bf16x8 __attribute__((ext_vector_type(8)));

__device__ __forceinline__ unsigned bf_rne(float f) {
  unsigned u = __float_as_uint(f);
  return (u + 0x7fffu + ((u >> 16) & 1u)) >> 16;   // RNE f32->bf16 (no NaN in data)
}
__device__ __forceinline__ unsigned pack2(float lo, float hi) {
  return bf_rne(lo) | (bf_rne(hi) << 16);
}

// ---------------------------------------------------------------------------
// numpy pairwise_sum emulation (exact): PASSED absmax 0.0 in R2..R5.
// ---------------------------------------------------------------------------
__device__ __forceinline__ float np_pw128_sumsq(const float* __restrict__ a) {
  float r0 = a[0]*a[0], r1 = a[1]*a[1], r2 = a[2]*a[2], r3 = a[3]*a[3];
  float r4 = a[4]*a[4], r5 = a[5]*a[5], r6 = a[6]*a[6], r7 = a[7]*a[7];
  for (int i = 8; i < 128; i += 8) {
    r0 += a[i+0]*a[i+0]; r1 += a[i+1]*a[i+1];
    r2 += a[i+2]*a[i+2]; r3 += a[i+3]*a[i+3];
    r4 += a[i+4]*a[i+4]; r5 += a[i+5]*a[i+5];
    r6 += a[i+6]*a[i+6]; r7 += a[i+7]*a[i+7];
  }
  return ((r0+r1)+(r2+r3))+((r4+r5)+(r6+r7));
}

__global__ __launch_bounds__(256) void vq_sumsq(const float* __restrict__ src,
                                                float* __restrict__ dst, int nrows) {
  int gid  = blockIdx.x * 256 + threadIdx.x;
  int row  = gid >> 1, half = gid & 1;
  if (row >= nrows) return;
  float s = np_pw128_sumsq(src + (size_t)row * DIM + half * 128);
  float o = __shfl_xor(s, 1);
  if (half == 0) dst[row] = s + o;     // fl(s0 + s1), numpy order
}

// ---------------------------------------------------------------------------
// NEW PATH
// ---------------------------------------------------------------------------

// init small arrays (ws poisoned 0xAA by harness)
__global__ __launch_bounds__(256) void vq_init(unsigned* __restrict__ hist,
                                               unsigned* __restrict__ bcnt,
                                               unsigned* __restrict__ ovf,
                                               unsigned long long* __restrict__ best) {
  int i = blockIdx.x * 256 + threadIdx.x;      // grid 128*256 = 32768
  ovf[i]  = 0u;
  best[i] = ~0ull;
  if (i < K_EMB) hist[i] = 0u;
  if (i < 128)   bcnt[i] = 0u;
}

// E f32 -> bf16 in MFMA-fragment-tile order:
//   tile t = cfg*8 + ks (cfg<512: 16-code frag; ks<8: 32-k step), 1 KB each.
//   lane l in tile: code = cfg*16 + (l&15), k = (ks*4 + (l>>4))*8 .. +8.
// A 128-code chunk = 64 consecutive tiles = 64 KB contiguous -> linear LDS copy.
__global__ __launch_bounds__(256) void vq_cvt_frag(const float* __restrict__ E,
                                                   uint4* __restrict__ Eb) {
  int t = blockIdx.x * 256 + threadIdx.x;      // 0..262143 (tile*64 + lane)
  int tile = t >> 6, l = t & 63;
  int cfg = tile >> 3, ks = tile & 7;
  int code = cfg * 16 + (l & 15);
  int k0 = (ks * 4 + (l >> 4)) * 8;
  const float4* src = (const float4*)(E + (size_t)code * DIM + k0);
  float4 a = src[0], b = src[1];
  uint4 o;
  o.x = pack2(a.x, a.y); o.y = pack2(a.z, a.w);
  o.z = pack2(b.x, b.y); o.w = pack2(b.z, b.w);
  Eb[t] = o;
}

// ---------------------------------------------------------------------------
// Single-pass MFMA approx-distance + per-(row, 64-code-sub) min.
// 512 thr / 8 waves; wave (wrg = w>>2: 64-row group, wcg = w&3: 32-col group).
// acc[4][2] 16x16 frags: per k-step 6 ds_read_b128 feed 8 MFMA (21 FLOP/B).
// X tile (128 rows) in LDS (R5 swizzle); E chunk (128 codes, fragment tiles)
// single-buffered with register prefetch (R4/R5-proven).
// Writes cmin[sub(128)][row(32768)] of g = fmaf(-2, b_hat, c)  (relative dist).
// ---------------------------------------------------------------------------
__global__ __launch_bounds__(512, 2) void vq_mfma_min(
    const float* __restrict__ X, const uint4* __restrict__ Eb,
    const float* __restrict__ C, float* __restrict__ cmin_g) {
  __shared__ __align__(16) unsigned short xs[128 * 256];   // 64 KB
  __shared__ __align__(16) unsigned short es[128 * 256];   // 64 KB
  __shared__ float lds2[4][128];                           // per-colwave row mins

  const int tid  = threadIdx.x;
  const int lane = tid & 63, w = tid >> 6;
  const int lr   = lane & 15, lg = lane >> 4;
  const int wrg  = w >> 2, wcg = w & 3;
  const int row0 = blockIdx.x * 128;

  uint4 pf[8];
#pragma unroll
  for (int i = 0; i < 8; ++i) pf[i] = Eb[tid + i * 512];   // prefetch chunk 0

  // stage X tile (f32 -> bf16, swizzled exactly as R5)
  {
    const float4* Xg = (const float4*)(X + (size_t)row0 * DIM);
#pragma unroll
    for (int i = 0; i < 8; ++i) {
      int u = tid + i * 512;                     // 0..4095
      int r = u >> 5, kb = u & 31;
      float4 a = Xg[2 * u], b = Xg[2 * u + 1];
      uint4 o;
      o.x = pack2(a.x, a.y); o.y = pack2(a.z, a.w);
      o.z = pack2(b.x, b.y); o.w = pack2(b.z, b.w);
      *(uint4*)(xs + (r * 256 + ((kb ^ (r & 31)) * 8))) = o;
    }
  }
#pragma unroll
  for (int i = 0; i < 8; ++i)                    // write chunk 0
    *(uint4*)(es + (size_t)(tid + i * 512) * 8) = pf[i];
  __syncthreads();

  for (int c = 0; c < 64; ++c) {
    if (c + 1 < 64) {
#pragma unroll
      for (int i = 0; i < 8; ++i)
        pf[i] = Eb[(size_t)(c + 1) * 4096 + tid + i * 512];
    }

    f32x4 acc[4][2];
#pragma unroll
    for (int rf = 0; rf < 4; ++rf)
#pragma unroll
      for (int cf = 0; cf < 2; ++cf)
        acc[rf][cf] = (f32x4){0.f, 0.f, 0.f, 0.f};

#pragma unroll
    for (int ks = 0; ks < 8; ++ks) {
      bf16x8 av[4], bv[2];
#pragma unroll
      for (int rf = 0; rf < 4; ++rf) {
        int row = wrg * 64 + rf * 16 + lr;
        av[rf] = *(const bf16x8*)(xs + row * 256 + (((ks * 4 + lg) ^ (row & 31)) * 8));
      }
#pragma unroll
      for (int cf = 0; cf < 2; ++cf)
        bv[cf] = *(const bf16x8*)(es + ((((wcg * 2 + cf) * 8 + ks) * 64 + lane) * 8));
#pragma unroll
      for (int rf = 0; rf < 4; ++rf)
#pragma unroll
        for (int cf = 0; cf < 2; ++cf)
          acc[rf][cf] = __builtin_amdgcn_mfma_f32_16x16x32_bf16(av[rf], bv[cf], acc[rf][cf], 0, 0, 0);
    }

    // g = c - 2*b_hat (relative distance), reduce to per-row min over 32 cols
    const int   cb = c * 128 + wcg * 32;
    const float c0 = C[cb + lr];
    const float c1 = C[cb + 16 + lr];
#pragma unroll
    for (int rf = 0; rf < 4; ++rf)
#pragma unroll
      for (int rg = 0; rg < 4; ++rg) {
        float m = fminf(fmaf(-2.0f, acc[rf][0][rg], c0),
                        fmaf(-2.0f, acc[rf][1][rg], c1));
        m = fminf(m, __shfl_xor(m, 1));
        m = fminf(m, __shfl_xor(m, 2));
        m = fminf(m, __shfl_xor(m, 4));
        m = fminf(m, __shfl_xor(m, 8));
        if (lr == 0) lds2[wcg][wrg * 64 + rf * 16 + lg * 4 + rg] = m;
      }
    __syncthreads();

    if (tid < 256) {   // combine col-wave pairs -> 64-code sub mins -> global
      int sub = tid >> 7, rl = tid & 127;
      float v = fminf(lds2[sub * 2][rl], lds2[sub * 2 + 1][rl]);
      cmin_g[(size_t)(c * 2 + sub) * N_ROWS + row0 + rl] = v;
    }
    if (c + 1 < 64) {
#pragma unroll
      for (int i = 0; i < 8; ++i)
        *(uint4*)(es + (size_t)(tid + i * 512) * 8) = pf[i];
    }
    __syncthreads();
  }
}

// ---------------------------------------------------------------------------
// Flag subchunks within window of the row's final min; bucket by subchunk.
// W = sqrt(a)*8e-6 (R5-proven stochastic bf16 term) + 1.8e-4 (rounding-split
// consts + headroom for the relative-g formulation).
// ---------------------------------------------------------------------------
__global__ __launch_bounds__(256) void vq_flag(
    const float* __restrict__ cmin, const float* __restrict__ A,
    unsigned* __restrict__ bcnt, int* __restrict__ buckets,
    unsigned* __restrict__ ovf) {
  int row = blockIdx.x * 256 + threadIdx.x;
  float m = INFINITY;
  for (int s = 0; s < 128; ++s)
    m = fminf(m, cmin[(size_t)s * N_ROWS + row]);
  float thr = m + (sqrtf(A[row]) * 8e-6f + 1.8e-4f);
  for (int s = 0; s < 128; ++s) {
    if (cmin[(size_t)s * N_ROWS + row] <= thr) {
      unsigned p = atomicAdd(&bcnt[s], 1u);
      if (p < BCAP) buckets[s * BCAP + p] = row;
      else          ovf[row] = 1u;
    }
  }
}

// ---------------------------------------------------------------------------
// Sparse exact: per (row, 64-code sub) pair, one wave, lane <-> code.
// E sub staged in LDS as exact f32 (code-major, padded); x row staged per
// wave. Chain is the R2-proven ascending fmaf order; d = (a - 2b) + c.
// Result merged across subs via atomicMin on packed (f32bits(d)<<32 | j):
// d > 0 always so float-bit order == float order; low word = numpy
// first-index tie-break.
// ---------------------------------------------------------------------------
__global__ __launch_bounds__(256) void vq_exact(
    const float* __restrict__ X, const float* __restrict__ E,
    const float* __restrict__ A, const float* __restrict__ C,
    const unsigned* __restrict__ bcnt, const int* __restrict__ buckets,
    unsigned long long* __restrict__ best) {
  __shared__ float e_lds[64][260];     // 64 codes x 256 k, +4 pad
  __shared__ float xr[4][256];
  const int tid  = threadIdx.x;
  const int lane = tid & 63, w = tid >> 6;
  const int bk   = blockIdx.x >> 1, half = blockIdx.x & 1;

#pragma unroll
  for (int i = 0; i < 16; ++i) {       // stage E sub (exact f32 copy)
    int u = tid + i * 256;             // 0..4095
    int code = u >> 6, koff = (u & 63) * 4;
    float4 v = *(const float4*)(E + (size_t)(bk * 64 + code) * DIM + koff);
    *(float4*)(&e_lds[code][koff]) = v;
  }
  __syncthreads();

  int n = (int)bcnt[bk]; if (n > BCAP) n = BCAP;
  const int   j  = bk * 64 + lane;
  const float cj = C[j];

  for (int p = half * 4 + w; p < n; p += 8) {
    int row = buckets[bk * BCAP + p];
    *(float4*)(&xr[w][lane * 4]) = *(const float4*)(X + (size_t)row * DIM + lane * 4);
    asm volatile("s_waitcnt lgkmcnt(0)" ::: "memory");   // wave-level x visibility
    float a_r = A[row];
    float acc = 0.f;
#pragma unroll 4
    for (int kq = 0; kq < 64; ++kq) {
      float4 xv = *(const float4*)(&xr[w][kq * 4]);
      float4 ev = *(const float4*)(&e_lds[lane][kq * 4]);
      acc = fmaf(xv.x, ev.x, acc); acc = fmaf(xv.y, ev.y, acc);
      acc = fmaf(xv.z, ev.z, acc); acc = fmaf(xv.w, ev.w, acc);
    }
    float bd = (a_r - 2.0f * acc) + cj;
    int   bj = j;
    for (int mm = 1; mm < 64; mm <<= 1) {
      float od = __shfl_xor(bd, mm);
      int   oj = __shfl_xor(bj, mm);
      if (od < bd || (od == bd && oj < bj)) { bd = od; bj = oj; }
    }
    if (lane == 0) {
      unsigned long long pk = ((unsigned long long)__float_as_uint(bd) << 32) |
                              (unsigned)bj;
      atomicMin(&best[row], pk);
    }
  }
}

// unpack best -> idx/idxf; bucket-overflow rows get an exact full scan
__global__ __launch_bounds__(256) void vq_finish(
    const float* __restrict__ X, const float* __restrict__ E,
    const float* __restrict__ A, const float* __restrict__ C,
    const unsigned* __restrict__ ovf, const unsigned long long* __restrict__ best,
    int* __restrict__ idx_out, float* __restrict__ idxf_out) {
  int row  = blockIdx.x * 4 + (threadIdx.x >> 6);
  int lane = threadIdx.x & 63;
  if (!ovf[row]) {
    if (lane == 0) {
      int j = (int)(best[row] & 0xffffffffu);
      idx_out[row]  = j;
      idxf_out[row] = (float)j;
    }
    return;
  }
  // exact full scan (R2-proven path)
  const float a_r = A[row];
  const float4* X4 = (const float4*)(X + (size_t)row * DIM);
  float bd = INFINITY; int bj = 0x7fffffff;
  for (int j = lane; j < K_EMB; j += 64) {
    const float4* E4 = (const float4*)(E + (size_t)j * DIM);
    float acc = 0.f;
    for (int kb = 0; kb < 64; ++kb) {
      float4 xv = X4[kb], ev = E4[kb];
      acc = fmaf(xv.x, ev.x, acc); acc = fmaf(xv.y, ev.y, acc);
      acc = fmaf(xv.z, ev.z, acc); acc = fmaf(xv.w, ev.w, acc);
    }
    float d = (a_r - 2.0f * acc) + C[j];
    if (d < bd || (d == bd && j < bj)) { bd = d; bj = j; }
  }
  for (int m = 1; m < 64; m <<= 1) {
    float od = __shfl_xor(bd, m);
    int   oj = __shfl_xor(bj, m);
    if (od < bd || (od == bd && oj < bj)) { bd = od; bj = oj; }
  }
  if (lane == 0) { idx_out[row] = bj; idxf_out[row] = (float)bj; }
}

// ---------------------------------------------------------------------------
// R5 FALLBACK PATH (proven, absmax 0.0 @ 916us) — used if ws too small
// ---------------------------------------------------------------------------
__global__ __launch_bounds__(256) void vq_cvt(const float* __restrict__ E,
                                              uint4* __restrict__ Eb) {
  int u = blockIdx.x * 256 + threadIdx.x;
  const float4* src = (const float4*)E + (size_t)u * 2;
  float4 a = src[0], b = src[1];
  uint4 o;
  o.x = pack2(a.x, a.y); o.y = pack2(a.z, a.w);
  o.z = pack2(b.x, b.y); o.w = pack2(b.z, b.w);
  Eb[u] = o;
}

__global__ __launch_bounds__(512, 1) void vq_mfma_cand(
    const float* __restrict__ X, const uint4* __restrict__ Eb,
    const float* __restrict__ A, const float* __restrict__ C,
    unsigned* __restrict__ gcnt, int* __restrict__ glist) {
  __shared__ __align__(16) unsigned short xs[128 * 256];
  __shared__ __align__(16) unsigned short es[2][64 * 256];
  __shared__ int      rowmin[128];
  __shared__ unsigned cnt[128];
  __shared__ int      list[128 * CAP];

  const int tid  = threadIdx.x;
  const int lane = tid & 63, w = tid >> 6;
  const int lr   = lane & 15, lg = lane >> 4;
  const int wr   = (w >> 1) * 32, wc = (w & 1) * 32;
  const int row0 = blockIdx.x * 128;

  if (tid < 128) { rowmin[tid] = 0x7f800000; cnt[tid] = 0u; }

  {
    const float4* Xg = (const float4*)(X + (size_t)row0 * DIM);
#pragma unroll
    for (int i = 0; i < 8; ++i) {
      int u = tid + i * 512;
      int r = u >> 5, kb = u & 31;
      float4 a = Xg[2 * u], b = Xg[2 * u + 1];
      uint4 o;
      o.x = pack2(a.x, a.y); o.y = pack2(a.z, a.w);
      o.z = pack2(b.x, b.y); o.w = pack2(b.z, b.w);
      *(uint4*)(xs + (r * 256 + ((kb ^ (r & 31)) * 8))) = o;
    }
  }

  float a_pre[8], w_pre[8];
#pragma unroll
  for (int rf = 0; rf < 2; ++rf)
#pragma unroll
    for (int rg = 0; rg < 4; ++rg) {
      float a = A[row0 + wr + rf * 16 + lg * 4 + rg];
      a_pre[rf * 4 + rg] = a;
      w_pre[rf * 4 + rg] = sqrtf(a) * 8e-6f + 1.3e-4f;
    }

  uint4 pf[4];
#define LOADC(c)                                                         \
  {                                                                      \
    _Pragma("unroll")                                                    \
    for (int i = 0; i < 4; ++i)                                          \
      pf[i] = Eb[(size_t)(c) * 2048 + tid + i * 512];                    \
  }
#define WRITEC(buf)                                                      \
  {                                                                      \
    _Pragma("unroll")                                                    \
    for (int i = 0; i < 4; ++i) {                                        \
      int u = tid + i * 512, cd = u >> 5, kb = u & 31;                   \
      *(uint4*)(es[buf] + (cd * 256 + ((kb ^ (cd & 31)) * 8))) = pf[i];  \
    }                                                                    \
  }

  LOADC(0);
  WRITEC(0);
  __syncthreads();

  float rmin[8], thr[8];
#pragma unroll
  for (int i = 0; i < 8; ++i) rmin[i] = INFINITY;

  for (int c = 0; c < 256; ++c) {
    const int cc  = c & 127;
    const int cur = c & 1;
    if (c + 1 < 256) LOADC((c + 1) & 127);

    f32x4 acc[2][2];
#pragma unroll
    for (int rf = 0; rf < 2; ++rf)
#pragma unroll
      for (int cf = 0; cf < 2; ++cf)
        acc[rf][cf] = (f32x4){0.f, 0.f, 0.f, 0.f};

    const unsigned short* eb = es[cur];
#pragma unroll
    for (int ks = 0; ks < 8; ++ks) {
      bf16x8 av[2], bv[2];
#pragma unroll
      for (int rf = 0; rf < 2; ++rf) {
        int row = wr + rf * 16 + lr;
        av[rf] = *(const bf16x8*)(xs + row * 256 + (((ks * 4 + lg) ^ (row & 31)) * 8));
      }
#pragma unroll
      for (int cf = 0; cf < 2; ++cf) {
        int cd = wc + cf * 16 + lr;
        bv[cf] = *(const bf16x8*)(eb + cd * 256 + (((ks * 4 + lg) ^ (cd & 31)) * 8));
      }
#pragma unroll
      for (int rf = 0; rf < 2; ++rf)
#pragma unroll
        for (int cf = 0; cf < 2; ++cf)
          acc[rf][cf] = __builtin_amdgcn_mfma_f32_16x16x32_bf16(av[rf], bv[cf], acc[rf][cf], 0, 0, 0);
    }

    const int   cb = cc * 64;
    const float c0 = C[cb + wc + lr];
    const float c1 = C[cb + wc + 16 + lr];
    if (c < 128) {
#pragma unroll
      for (int rf = 0; rf < 2; ++rf)
#pragma unroll
        for (int rg = 0; rg < 4; ++rg) {
          float a  = a_pre[rf * 4 + rg];
          float d0 = (a - 2.0f * acc[rf][0][rg]) + c0;
          float d1 = (a - 2.0f * acc[rf][1][rg]) + c1;
          rmin[rf * 4 + rg] = fminf(rmin[rf * 4 + rg], fminf(d0, d1));
        }
    } else {
#pragma unroll
      for (int rf = 0; rf < 2; ++rf)
#pragma unroll
        for (int rg = 0; rg < 4; ++rg) {
          float a  = a_pre[rf * 4 + rg];
          float d0 = (a - 2.0f * acc[rf][0][rg]) + c0;
          float d1 = (a - 2.0f * acc[rf][1][rg]) + c1;
          int   rl = wr + rf * 16 + lg * 4 + rg;
          float t  = thr[rf * 4 + rg];
          if (d0 <= t) {
            unsigned p = atomicAdd(&cnt[rl], 1u);
            if (p < CAP) list[rl * CAP + p] = cb + wc + lr;
          }
          if (d1 <= t) {
            unsigned p = atomicAdd(&cnt[rl], 1u);
            if (p < CAP) list[rl * CAP + p] = cb + wc + 16 + lr;
          }
        }
    }

    if (c == 127) {
#pragma unroll
      for (int i = 0; i < 8; ++i) {
#pragma unroll
        for (int m = 1; m < 16; m <<= 1)
          rmin[i] = fminf(rmin[i], __shfl_xor(rmin[i], m));
      }
      if (lr == 0) {
#pragma unroll
        for (int rf = 0; rf < 2; ++rf)
#pragma unroll
          for (int rg = 0; rg < 4; ++rg)
            atomicMin(&rowmin[wr + rf * 16 + lg * 4 + rg],
                      __float_as_int(rmin[rf * 4 + rg]));
      }
    }

    __syncthreads();

    if (c == 127) {
#pragma unroll
      for (int rf = 0; rf < 2; ++rf)
#pragma unroll
        for (int rg = 0; rg < 4; ++rg)
          thr[rf * 4 + rg] =
              __int_as_float(rowmin[wr + rf * 16 + lg * 4 + rg]) + w_pre[rf * 4 + rg];
    }

    if (c + 1 < 256) {
      WRITEC(cur ^ 1);
      __syncthreads();
    }
  }
  __syncthreads();

  if (tid < 128) {
    int row = row0 + tid;
    unsigned n = cnt[tid];
    gcnt[row] = n;
    unsigned m = n < CAP ? n : CAP;
    for (unsigned i = 0; i < m; ++i)
      glist[(size_t)row * CAP + i] = list[tid * CAP + i];
  }
}

__global__ __launch_bounds__(256) void vq_recheck(
    const float* __restrict__ X, const float* __restrict__ E,
    const float* __restrict__ A, const float* __restrict__ C,
    const unsigned* __restrict__ gcnt, const int* __restrict__ glist,
    int* __restrict__ idx_out, float* __restrict__ idxf_out) {
  int row  = blockIdx.x * 4 + (threadIdx.x >> 6);
  int lane = threadIdx.x & 63;
  unsigned n = gcnt[row];
  const float a_r = A[row];
  const float4* X4 = (const float4*)(X + (size_t)row * DIM);

  float bd = INFINITY; int bj = 0x7fffffff;
  if (n <= CAP) {
    if (lane < (int)n) {
      int j = glist[(size_t)row * CAP + lane];
      const float4* E4 = (const float4*)(E + (size_t)j * DIM);
      float acc = 0.f;
      for (int kb = 0; kb < 64; ++kb) {
        float4 xv = X4[kb], ev = E4[kb];
        acc = fmaf(xv.x, ev.x, acc); acc = fmaf(xv.y, ev.y, acc);
        acc = fmaf(xv.z, ev.z, acc); acc = fmaf(xv.w, ev.w, acc);
      }
      bd = (a_r - 2.0f * acc) + C[j]; bj = j;
    }
  } else {
    for (int j = lane; j < K_EMB; j += 64) {
      const float4* E4 = (const float4*)(E + (size_t)j * DIM);
      float acc = 0.f;
      for (int kb = 0; kb < 64; ++kb) {
        float4 xv = X4[kb], ev = E4[kb];
        acc = fmaf(xv.x, ev.x, acc); acc = fmaf(xv.y, ev.y, acc);
        acc = fmaf(xv.z, ev.z, acc); acc = fmaf(xv.w, ev.w, acc);
      }
      float d = (a_r - 2.0f * acc) + C[j];
      if (d < bd || (d == bd && j < bj)) { bd = d; bj = j; }
    }
  }
  for (int m = 1; m < 64; m <<= 1) {
    float od = __shfl_xor(bd, m);
    int   oj = __shfl_xor(bj, m);
    if (od < bd || (od == bd && oj < bj)) { bd = od; bj = oj; }
  }
  if (lane == 0) { idx_out[row] = bj; idxf_out[row] = (float)bj; }
}

// R2 brute-force (ultra-fallback)
__global__ __launch_bounds__(256) void vq_argmin(const float* __restrict__ X,
                                                 const float* __restrict__ E,
                                                 const float* __restrict__ A,
                                                 const float* __restrict__ C,
                                                 int* __restrict__ idx_out,
                                                 float* __restrict__ idxf_out) {
  __shared__ float4 xs4[64 * 64];
  const int tid  = threadIdx.x;
  const int rl   = tid >> 2;
  const int cg   = tid & 3;
  const int row0 = blockIdx.x * 64;

  const float4* Xg = (const float4*)(X + (size_t)row0 * DIM);
  for (int it = 0; it < 16; ++it) {
    int f4 = tid + it * 256;
    float4 v = Xg[f4];
    int r = f4 >> 6, kb = f4 & 63;
    xs4[r * 64 + (kb ^ (r & 7))] = v;
  }
  __syncthreads();

  const float a_r = A[row0 + rl];
  const int   swq = rl & 7;
  const float4* xrow = xs4 + rl * 64;

  float bd = INFINITY;
  int   bj = 0x7fffffff;

  for (int tile = 0; tile < K_EMB; tile += 16) {
    const int j0 = tile + cg * 4;
    const float4* e0 = (const float4*)(E + (size_t)(j0 + 0) * DIM);
    const float4* e1 = (const float4*)(E + (size_t)(j0 + 1) * DIM);
    const float4* e2 = (const float4*)(E + (size_t)(j0 + 2) * DIM);
    const float4* e3 = (const float4*)(E + (size_t)(j0 + 3) * DIM);
    float acc0 = 0.f, acc1 = 0.f, acc2 = 0.f, acc3 = 0.f;
#pragma unroll 4
    for (int kb = 0; kb < 64; ++kb) {
      const float4 xv = xrow[kb ^ swq];
      const float4 q0 = e0[kb], q1 = e1[kb], q2 = e2[kb], q3 = e3[kb];
      acc0 = fmaf(xv.x, q0.x, acc0); acc0 = fmaf(xv.y, q0.y, acc0);
      acc0 = fmaf(xv.z, q0.z, acc0); acc0 = fmaf(xv.w, q0.w, acc0);
      acc1 = fmaf(xv.x, q1.x, acc1); acc1 = fmaf(xv.y, q1.y, acc1);
      acc1 = fmaf(xv.z, q1.z, acc1); acc1 = fmaf(xv.w, q1.w, acc1);
      acc2 = fmaf(xv.x, q2.x, acc2); acc2 = fmaf(xv.y, q2.y, acc2);
      acc2 = fmaf(xv.z, q2.z, acc2); acc2 = fmaf(xv.w, q2.w, acc2);
      acc3 = fmaf(xv.x, q3.x, acc3); acc3 = fmaf(xv.y, q3.y, acc3);
      acc3 = fmaf(xv.z, q3.z, acc3); acc3 = fmaf(xv.w, q3.w, acc3);
    }
    const float d0 = (a_r - 2.0f * acc0) + C[j0 + 0];
    const float d1 = (a_r - 2.0f * acc1) + C[j0 + 1];
    const float d2 = (a_r - 2.0f * acc2) + C[j0 + 2];
    const float d3 = (a_r - 2.0f * acc3) + C[j0 + 3];
    if (d0 < bd) { bd = d0; bj = j0 + 0; }
    if (d1 < bd) { bd = d1; bj = j0 + 1; }
    if (d2 < bd) { bd = d2; bj = j0 + 2; }
    if (d3 < bd) { bd = d3; bj = j0 + 3; }
  }
  for (int m = 1; m < 4; m <<= 1) {
    float od = __shfl_xor(bd, m);
    int   oj = __shfl_xor(bj, m);
    if (od < bd || (od == bd && oj < bj)) { bd = od; bj = oj; }
  }
  if (cg == 0) {
    int row = row0 + rl;
    idx_out[row]  = bj;
    idxf_out[row] = (float)bj;
  }
}

// ---------------------------------------------------------------------------
// quantized_st + loss partials / hist / scalars (unchanged, PASSED)
// ---------------------------------------------------------------------------
__global__ __launch_bounds__(256) void vq_quant(const float* __restrict__ X,
                                                const float* __restrict__ E,
                                                const int* __restrict__ idx,
                                                float* __restrict__ out_qst,
                                                double* __restrict__ partials) {
  int gid  = blockIdx.x * 256 + threadIdx.x;
  int base = gid * 4;
  int row  = base >> 8;
  int k    = base & 255;
  int j    = idx[row];
  const float4 xv = *(const float4*)(X + (size_t)base);
  const float4 ev = *(const float4*)(E + (size_t)j * DIM + k);
  float4 o;
  float d0 = ev.x - xv.x, d1 = ev.y - xv.y, d2 = ev.z - xv.z, d3 = ev.w - xv.w;
  o.x = xv.x + d0; o.y = xv.y + d1; o.z = xv.z + d2; o.w = xv.w + d3;
  double s = (double)d0 * d0 + (double)d1 * d1 + (double)d2 * d2 + (double)d3 * d3;
  *(float4*)(out_qst + (size_t)base) = o;

  for (int m = 32; m; m >>= 1) s += __shfl_xor(s, m);
  __shared__ double wsum[4];
  int lane = threadIdx.x & 63, w = threadIdx.x >> 6;
  if (lane == 0) wsum[w] = s;
  __syncthreads();
  if (threadIdx.x == 0)
    partials[blockIdx.x] = (wsum[0] + wsum[1]) + (wsum[2] + wsum[3]);
}

__global__ void vq_zero(unsigned* counts) {
  int i = blockIdx.x * 256 + threadIdx.x;
  if (i < K_EMB) counts[i] = 0u;
}

__global__ void vq_hist(const int* __restrict__ idx, unsigned* __restrict__ counts) {
  int i = blockIdx.x * 256 + threadIdx.x;
  if (i < N_ROWS) atomicAdd(&counts[idx[i]], 1u);
}

__global__ __launch_bounds__(256) void vq_scalars(const double* __restrict__ partials,
                                                  const unsigned* __restrict__ counts,
                                                  float* __restrict__ out_loss,
                                                  float* __restrict__ out_perp) {
  __shared__ double red[256];
  int t = threadIdx.x;
  double s = 0.0;
  for (int i = t; i < 8192; i += 256) s += partials[i];
  red[t] = s;
  __syncthreads();
  for (int o = 128; o; o >>= 1) { if (t < o) red[t] += red[t + o]; __syncthreads(); }
  double mse = red[0] / (double)((size_t)N_ROWS * DIM);
  __syncthreads();

  double p = 0.0;
  for (int i = t; i < K_EMB; i += 256) {
    double pr = (double)counts[i] / (double)N_ROWS;
    p += pr * log(pr + 1e-10);
  }
  red[t] = p;
  __syncthreads();
  for (int o = 128; o; o >>= 1) { if (t < o) red[t] += red[t + o]; __syncthreads(); }
  if (t == 0) {
    float m = (float)mse;
    out_loss[0] = m + 0.25f * m;
    out_perp[0] = (float)exp(-red[0]);
  }
}

extern "C" void kernel_launch(void* const* d_in, const int* in_sizes, int n_in,
                              void* d_out, int out_size, void* d_ws, size_t ws_size,
                              hipStream_t stream) {
  const float* X = (const float*)d_in[0];   // [32768, 256]
  const float* E = (const float*)d_in[1];   // [8192, 256]
  float* out  = (float*)d_out;
  float* qst  = out;
  float* loss = out + 8388608;
  float* perp = out + 8388609;
  float* idxf = out + 8388610;

  // shared low region (both paths):
  float*    A        = (float*)d_ws;                            //       0
  float*    C        = (float*)((char*)d_ws + 131072);          //  131072
  int*      idx      = (int*)((char*)d_ws + 163840);            //  163840
  unsigned* hist     = (unsigned*)((char*)d_ws + 294912);       //  294912
  double*   partials = (double*)((char*)d_ws + 327680);         //  327680

  vq_sumsq <<<256, 256, 0, stream>>>(X, A, N_ROWS);
  vq_sumsq <<<64,  256, 0, stream>>>(E, C, K_EMB);

  if (ws_size >= 23855616) {
    // new path layout
    unsigned long long* best = (unsigned long long*)((char*)d_ws + 393216);
    unsigned* ovf      = (unsigned*)((char*)d_ws + 655360);
    unsigned* bcnt     = (unsigned*)((char*)d_ws + 786432);
    int*      buckets  = (int*)((char*)d_ws + 786944);
    uint4*    Eb       = (uint4*)((char*)d_ws + 2884096);
    float*    cmin     = (float*)((char*)d_ws + 7078400);

    vq_init     <<<128,  256, 0, stream>>>(hist, bcnt, ovf, best);
    vq_cvt_frag <<<1024, 256, 0, stream>>>(E, Eb);
    vq_mfma_min <<<256,  512, 0, stream>>>(X, Eb, C, cmin);
    vq_flag     <<<128,  256, 0, stream>>>(cmin, A, bcnt, buckets, ovf);
    vq_exact    <<<256,  256, 0, stream>>>(X, E, A, C, bcnt, buckets, best);
    vq_finish   <<<8192, 256, 0, stream>>>(X, E, A, C, ovf, best, idx, idxf);
  } else if (ws_size >= 7864320) {
    // R5 path layout
    unsigned* ccnt  = (unsigned*)((char*)d_ws + 393216);
    int*      clist = (int*)((char*)d_ws + 524288);
    uint4*    EbO   = (uint4*)((char*)d_ws + 3670016);
    vq_zero      <<<32,   256, 0, stream>>>(hist);
    vq_cvt       <<<1024, 256, 0, stream>>>(E, EbO);
    vq_mfma_cand <<<256,  512, 0, stream>>>(X, EbO, A, C, ccnt, clist);
    vq_recheck   <<<8192, 256, 0, stream>>>(X, E, A, C, ccnt, clist, idx, idxf);
  } else {
    vq_zero   <<<32,  256, 0, stream>>>(hist);
    vq_argmin <<<512, 256, 0, stream>>>(X, E, A, C, idx, idxf);
  }

  vq_quant  <<<8192, 256, 0, stream>>>(X, E, idx, qst, partials);
  vq_hist   <<<128,  256, 0, stream>>>(idx, hist);
  vq_scalars<<<1,    256, 0, stream>>>(partials, hist, loss, perp);
}

// Round 7
// 846.970 us; speedup vs baseline: 1.3753x; 1.3753x over previous
//
#include <hip/hip_runtime.h>
#include <math.h>

// No automatic FMA contraction anywhere: numpy-emulation arithmetic
// (square-then-add, sub-then-add) must round exactly like the reference.
// Explicit fmaf() stays fused regardless.
#pragma clang fp contract(off)

#define N_ROWS 32768
#define DIM    256
#define K_EMB  8192
#define CAP    24

typedef float  f32x4  __attribute__((ext_vector_type(4)));
typedef short  bf16x8 __attribute__((ext_vector_type(8)));

__device__ __forceinline__ unsigned bf_rne(float f) {
  unsigned u = __float_as_uint(f);
  return (u + 0x7fffu + ((u >> 16) & 1u)) >> 16;   // RNE f32->bf16 (no NaN in data)
}
__device__ __forceinline__ unsigned pack2(float lo, float hi) {
  return bf_rne(lo) | (bf_rne(hi) << 16);
}

// ---------------------------------------------------------------------------
// numpy pairwise_sum emulation (exact order, vectorized loads): R2..R6 proven.
// ---------------------------------------------------------------------------
__device__ __forceinline__ float np_pw128_sumsq(const float* __restrict__ a) {
  float4 v0 = *(const float4*)(a);
  float4 v1 = *(const float4*)(a + 4);
  float r0 = v0.x*v0.x, r1 = v0.y*v0.y, r2 = v0.z*v0.z, r3 = v0.w*v0.w;
  float r4 = v1.x*v1.x, r5 = v1.y*v1.y, r6 = v1.z*v1.z, r7 = v1.w*v1.w;
  for (int i = 8; i < 128; i += 8) {
    float4 w0 = *(const float4*)(a + i);
    float4 w1 = *(const float4*)(a + i + 4);
    r0 += w0.x*w0.x; r1 += w0.y*w0.y; r2 += w0.z*w0.z; r3 += w0.w*w0.w;
    r4 += w1.x*w1.x; r5 += w1.y*w1.y; r6 += w1.z*w1.z; r7 += w1.w*w1.w;
  }
  return ((r0+r1)+(r2+r3))+((r4+r5)+(r6+r7));
}

__global__ __launch_bounds__(256) void vq_sumsq(const float* __restrict__ src,
                                                float* __restrict__ dst, int nrows) {
  int gid  = blockIdx.x * 256 + threadIdx.x;
  int row  = gid >> 1, half = gid & 1;
  if (row >= nrows) return;
  float s = np_pw128_sumsq(src + (size_t)row * DIM + half * 128);
  float o = __shfl_xor(s, 1);
  if (half == 0) dst[row] = s + o;     // fl(s0 + s1), numpy order
}

// E f32 -> bf16 in MFMA-fragment-tile order (R6-proven):
//   tile t = cfg*8 + ks; lane l: code = cfg*16 + (l&15), k0 = (ks*4+(l>>4))*8.
// A 128-code chunk = 64 consecutive tiles = 64 KB contiguous (linear LDS copy).
__global__ __launch_bounds__(256) void vq_cvt_frag(const float* __restrict__ E,
                                                   uint4* __restrict__ Eb) {
  int t = blockIdx.x * 256 + threadIdx.x;      // 0..262143 (tile*64 + lane)
  int tile = t >> 6, l = t & 63;
  int cfg = tile >> 3, ks = tile & 7;
  int code = cfg * 16 + (l & 15);
  int k0 = (ks * 4 + (l >> 4)) * 8;
  const float4* src = (const float4*)(E + (size_t)code * DIM + k0);
  float4 a = src[0], b = src[1];
  uint4 o;
  o.x = pack2(a.x, a.y); o.y = pack2(a.z, a.w);
  o.z = pack2(b.x, b.y); o.w = pack2(b.z, b.w);
  Eb[t] = o;
}

// ---------------------------------------------------------------------------
// Two-pass MFMA candidate kernel, X-in-registers edition.
// 512 thr / 8 waves; wave w: wrg = w>>2 (64-row group), wcg = w&3 (32-col grp).
// av[4][8] (the wave's 64 rows x 256 k, bf16) filled ONCE from an LDS-staged
// X tile, then held in VGPRs for all 128 chunk-iterations: inner loop reads
// only 2 B-fragments per ks (vs 6 reads in R5) -> LDS-issue bound ~halved,
// and the freed LDS gives a 2x64KB double buffer for 128-code chunks.
// Pass 1 (c=0..63): per-lane min of g = c - 2*b_hat (row-term-free, R6).
// Transition: shfl-reduce over lr, float stores to lds2[4][128], combine,
// thr = gmin + W(a), W = sqrt(a)*8e-6 + 1.8e-4 (R5/R6-proven window).
// Pass 2 (c=64..127): append candidates with g <= thr (R5-proven logic).
// ---------------------------------------------------------------------------
__global__ __launch_bounds__(512, 2) void vq_mfma_cand2(
    const float* __restrict__ X, const uint4* __restrict__ Eb,
    const float* __restrict__ A, const float* __restrict__ C,
    unsigned* __restrict__ gcnt, int* __restrict__ glist) {
  __shared__ __align__(16) unsigned short es[2][128 * 256];  // 2 x 64 KB
  __shared__ float    lds2[4][128];
  __shared__ float    wwin[128];
  __shared__ unsigned cnt[128];
  __shared__ int      list[128 * CAP];

  const int tid  = threadIdx.x;        // 0..511
  const int lane = tid & 63, w = tid >> 6;
  const int lr   = lane & 15, lg = lane >> 4;
  const int wrg  = w >> 2, wcg = w & 3;
  const int row0 = blockIdx.x * 128;

  if (tid < 128) {
    cnt[tid]  = 0u;
    wwin[tid] = sqrtf(A[row0 + tid]) * 8e-6f + 1.8e-4f;
  }

  // stage X tile into es[0] as [128][256] bf16, R5 swizzle
  {
    const float4* Xg = (const float4*)(X + (size_t)row0 * DIM);
    unsigned short* xs = es[0];
#pragma unroll
    for (int i = 0; i < 8; ++i) {
      int u = tid + i * 512;                     // 0..4095
      int r = u >> 5, kb = u & 31;
      float4 a = Xg[2 * u], b = Xg[2 * u + 1];
      uint4 o;
      o.x = pack2(a.x, a.y); o.y = pack2(a.z, a.w);
      o.z = pack2(b.x, b.y); o.w = pack2(b.z, b.w);
      *(uint4*)(xs + (r * 256 + ((kb ^ (r & 31)) * 8))) = o;
    }
  }
  __syncthreads();

  // prefetch chunk 0 (global, overlaps the av ds_reads below)
  uint4 pf[8];
#pragma unroll
  for (int i = 0; i < 8; ++i) pf[i] = Eb[tid + i * 512];

  // fill av[4][8]: the wave's 64 rows, held in registers for the whole kernel
  bf16x8 av[4][8];
  {
    const unsigned short* xs = es[0];
#pragma unroll
    for (int rf = 0; rf < 4; ++rf) {
      int row = wrg * 64 + rf * 16 + lr;
#pragma unroll
      for (int ks = 0; ks < 8; ++ks)
        av[rf][ks] = *(const bf16x8*)(xs + row * 256 + (((ks * 4 + lg) ^ (row & 31)) * 8));
    }
  }
  __syncthreads();                     // av filled; es[0] free for chunk 0

#pragma unroll
  for (int i = 0; i < 8; ++i)
    *(uint4*)(es[0] + (size_t)(tid + i * 512) * 8) = pf[i];
  __syncthreads();

  float rt[16];                        // pass1: running min; pass2: threshold
#pragma unroll
  for (int i = 0; i < 16; ++i) rt[i] = INFINITY;

  for (int c = 0; c < 128; ++c) {
    const int cur = c & 1;
    if (c + 1 < 128) {
      const size_t off = (size_t)((c + 1) & 63) * 4096;
#pragma unroll
      for (int i = 0; i < 8; ++i) pf[i] = Eb[off + tid + i * 512];
    }

    f32x4 acc[4][2];
#pragma unroll
    for (int rf = 0; rf < 4; ++rf)
#pragma unroll
      for (int cf = 0; cf < 2; ++cf)
        acc[rf][cf] = (f32x4){0.f, 0.f, 0.f, 0.f};

    const unsigned short* eb = es[cur];
#pragma unroll
    for (int ks = 0; ks < 8; ++ks) {
      bf16x8 bv0 = *(const bf16x8*)(eb + ((((wcg * 2 + 0) * 8 + ks) * 64 + lane) * 8));
      bf16x8 bv1 = *(const bf16x8*)(eb + ((((wcg * 2 + 1) * 8 + ks) * 64 + lane) * 8));
#pragma unroll
      for (int rf = 0; rf < 4; ++rf) {
        acc[rf][0] = __builtin_amdgcn_mfma_f32_16x16x32_bf16(av[rf][ks], bv0, acc[rf][0], 0, 0, 0);
        acc[rf][1] = __builtin_amdgcn_mfma_f32_16x16x32_bf16(av[rf][ks], bv1, acc[rf][1], 0, 0, 0);
      }
    }

    // g = c - 2*b_hat : row-constant-free relative distance
    const int   cb = (c & 63) * 128 + wcg * 32;
    const float c0 = C[cb + lr];
    const float c1 = C[cb + 16 + lr];
    if (c < 64) {
#pragma unroll
      for (int rf = 0; rf < 4; ++rf)
#pragma unroll
        for (int rg = 0; rg < 4; ++rg) {
          float g0 = fmaf(-2.0f, acc[rf][0][rg], c0);
          float g1 = fmaf(-2.0f, acc[rf][1][rg], c1);
          rt[rf * 4 + rg] = fminf(rt[rf * 4 + rg], fminf(g0, g1));
        }
    } else {
#pragma unroll
      for (int rf = 0; rf < 4; ++rf)
#pragma unroll
        for (int rg = 0; rg < 4; ++rg) {
          float g0 = fmaf(-2.0f, acc[rf][0][rg], c0);
          float g1 = fmaf(-2.0f, acc[rf][1][rg], c1);
          int   rl = wrg * 64 + rf * 16 + lg * 4 + rg;
          float t  = rt[rf * 4 + rg];
          if (g0 <= t) {
            unsigned p = atomicAdd(&cnt[rl], 1u);
            if (p < CAP) list[rl * CAP + p] = cb + lr;
          }
          if (g1 <= t) {
            unsigned p = atomicAdd(&cnt[rl], 1u);
            if (p < CAP) list[rl * CAP + p] = cb + 16 + lr;
          }
        }
    }

    if (c == 63) {
      // transition: reduce per-lane mins over the 16 col-lanes, publish
#pragma unroll
      for (int i = 0; i < 16; ++i) {
#pragma unroll
        for (int m = 1; m < 16; m <<= 1)
          rt[i] = fminf(rt[i], __shfl_xor(rt[i], m));
      }
      if (lr == 0) {
#pragma unroll
        for (int rf = 0; rf < 4; ++rf)
#pragma unroll
          for (int rg = 0; rg < 4; ++rg)
            lds2[wcg][wrg * 64 + rf * 16 + lg * 4 + rg] = rt[rf * 4 + rg];
      }
    }

    __syncthreads();                   // es[cur] reads done; (c==63) mins out

    if (c == 63) {                     // thr = min over 4 col-groups + W
#pragma unroll
      for (int rf = 0; rf < 4; ++rf)
#pragma unroll
        for (int rg = 0; rg < 4; ++rg) {
          int rl = wrg * 64 + rf * 16 + lg * 4 + rg;
          float m = fminf(fminf(lds2[0][rl], lds2[1][rl]),
                          fminf(lds2[2][rl], lds2[3][rl]));
          rt[rf * 4 + rg] = m + wwin[rl];
        }
    }

    if (c + 1 < 128) {
      unsigned short* ew = es[cur ^ 1];
#pragma unroll
      for (int i = 0; i < 8; ++i)
        *(uint4*)(ew + (size_t)(tid + i * 512) * 8) = pf[i];
      __syncthreads();
    }
  }
  __syncthreads();

  if (tid < 128) {
    int row = row0 + tid;
    unsigned n = cnt[tid];
    gcnt[row] = n;
    unsigned m = n < CAP ? n : CAP;
    for (unsigned i = 0; i < m; ++i)
      glist[(size_t)row * CAP + i] = list[tid * CAP + i];
  }
}

// ---------------------------------------------------------------------------
// Exact recheck (R2/R5-proven): one wave per row; lanes take candidates, or
// full scan on overflow. Lex (d, j) min == numpy first-index.
// ---------------------------------------------------------------------------
__global__ __launch_bounds__(256) void vq_recheck(
    const float* __restrict__ X, const float* __restrict__ E,
    const float* __restrict__ A, const float* __restrict__ C,
    const unsigned* __restrict__ gcnt, const int* __restrict__ glist,
    int* __restrict__ idx_out, float* __restrict__ idxf_out) {
  int row  = blockIdx.x * 4 + (threadIdx.x >> 6);
  int lane = threadIdx.x & 63;
  unsigned n = gcnt[row];
  const float a_r = A[row];
  const float4* X4 = (const float4*)(X + (size_t)row * DIM);

  float bd = INFINITY; int bj = 0x7fffffff;
  if (n <= CAP) {
    if (lane < (int)n) {
      int j = glist[(size_t)row * CAP + lane];
      const float4* E4 = (const float4*)(E + (size_t)j * DIM);
      float acc = 0.f;
      for (int kb = 0; kb < 64; ++kb) {
        float4 xv = X4[kb], ev = E4[kb];
        acc = fmaf(xv.x, ev.x, acc); acc = fmaf(xv.y, ev.y, acc);
        acc = fmaf(xv.z, ev.z, acc); acc = fmaf(xv.w, ev.w, acc);
      }
      bd = (a_r - 2.0f * acc) + C[j]; bj = j;
    }
  } else {
    for (int j = lane; j < K_EMB; j += 64) {
      const float4* E4 = (const float4*)(E + (size_t)j * DIM);
      float acc = 0.f;
      for (int kb = 0; kb < 64; ++kb) {
        float4 xv = X4[kb], ev = E4[kb];
        acc = fmaf(xv.x, ev.x, acc); acc = fmaf(xv.y, ev.y, acc);
        acc = fmaf(xv.z, ev.z, acc); acc = fmaf(xv.w, ev.w, acc);
      }
      float d = (a_r - 2.0f * acc) + C[j];
      if (d < bd || (d == bd && j < bj)) { bd = d; bj = j; }
    }
  }
  for (int m = 1; m < 64; m <<= 1) {
    float od = __shfl_xor(bd, m);
    int   oj = __shfl_xor(bj, m);
    if (od < bd || (od == bd && oj < bj)) { bd = od; bj = oj; }
  }
  if (lane == 0) { idx_out[row] = bj; idxf_out[row] = (float)bj; }
}

// ---------------------------------------------------------------------------
// Exact brute-force argmin (R2-proven) — ws-too-small fallback.
// ---------------------------------------------------------------------------
__global__ __launch_bounds__(256) void vq_argmin(const float* __restrict__ X,
                                                 const float* __restrict__ E,
                                                 const float* __restrict__ A,
                                                 const float* __restrict__ C,
                                                 int* __restrict__ idx_out,
                                                 float* __restrict__ idxf_out) {
  __shared__ float4 xs4[64 * 64];
  const int tid  = threadIdx.x;
  const int rl   = tid >> 2;
  const int cg   = tid & 3;
  const int row0 = blockIdx.x * 64;

  const float4* Xg = (const float4*)(X + (size_t)row0 * DIM);
  for (int it = 0; it < 16; ++it) {
    int f4 = tid + it * 256;
    float4 v = Xg[f4];
    int r = f4 >> 6, kb = f4 & 63;
    xs4[r * 64 + (kb ^ (r & 7))] = v;
  }
  __syncthreads();

  const float a_r = A[row0 + rl];
  const int   swq = rl & 7;
  const float4* xrow = xs4 + rl * 64;

  float bd = INFINITY;
  int   bj = 0x7fffffff;

  for (int tile = 0; tile < K_EMB; tile += 16) {
    const int j0 = tile + cg * 4;
    const float4* e0 = (const float4*)(E + (size_t)(j0 + 0) * DIM);
    const float4* e1 = (const float4*)(E + (size_t)(j0 + 1) * DIM);
    const float4* e2 = (const float4*)(E + (size_t)(j0 + 2) * DIM);
    const float4* e3 = (const float4*)(E + (size_t)(j0 + 3) * DIM);
    float acc0 = 0.f, acc1 = 0.f, acc2 = 0.f, acc3 = 0.f;
#pragma unroll 4
    for (int kb = 0; kb < 64; ++kb) {
      const float4 xv = xrow[kb ^ swq];
      const float4 q0 = e0[kb], q1 = e1[kb], q2 = e2[kb], q3 = e3[kb];
      acc0 = fmaf(xv.x, q0.x, acc0); acc0 = fmaf(xv.y, q0.y, acc0);
      acc0 = fmaf(xv.z, q0.z, acc0); acc0 = fmaf(xv.w, q0.w, acc0);
      acc1 = fmaf(xv.x, q1.x, acc1); acc1 = fmaf(xv.y, q1.y, acc1);
      acc1 = fmaf(xv.z, q1.z, acc1); acc1 = fmaf(xv.w, q1.w, acc1);
      acc2 = fmaf(xv.x, q2.x, acc2); acc2 = fmaf(xv.y, q2.y, acc2);
      acc2 = fmaf(xv.z, q2.z, acc2); acc2 = fmaf(xv.w, q2.w, acc2);
      acc3 = fmaf(xv.x, q3.x, acc3); acc3 = fmaf(xv.y, q3.y, acc3);
      acc3 = fmaf(xv.z, q3.z, acc3); acc3 = fmaf(xv.w, q3.w, acc3);
    }
    const float d0 = (a_r - 2.0f * acc0) + C[j0 + 0];
    const float d1 = (a_r - 2.0f * acc1) + C[j0 + 1];
    const float d2 = (a_r - 2.0f * acc2) + C[j0 + 2];
    const float d3 = (a_r - 2.0f * acc3) + C[j0 + 3];
    if (d0 < bd) { bd = d0; bj = j0 + 0; }
    if (d1 < bd) { bd = d1; bj = j0 + 1; }
    if (d2 < bd) { bd = d2; bj = j0 + 2; }
    if (d3 < bd) { bd = d3; bj = j0 + 3; }
  }
  for (int m = 1; m < 4; m <<= 1) {
    float od = __shfl_xor(bd, m);
    int   oj = __shfl_xor(bj, m);
    if (od < bd || (od == bd && oj < bj)) { bd = od; bj = oj; }
  }
  if (cg == 0) {
    int row = row0 + rl;
    idx_out[row]  = bj;
    idxf_out[row] = (float)bj;
  }
}

// ---------------------------------------------------------------------------
// quantized_st + loss partials / hist / scalars (R2..R6 proven)
// ---------------------------------------------------------------------------
__global__ __launch_bounds__(256) void vq_quant(const float* __restrict__ X,
                                                const float* __restrict__ E,
                                                const int* __restrict__ idx,
                                                float* __restrict__ out_qst,
                                                double* __restrict__ partials) {
  int gid  = blockIdx.x * 256 + threadIdx.x;
  int base = gid * 4;
  int row  = base >> 8;
  int k    = base & 255;
  int j    = idx[row];
  const float4 xv = *(const float4*)(X + (size_t)base);
  const float4 ev = *(const float4*)(E + (size_t)j * DIM + k);
  float4 o;
  float d0 = ev.x - xv.x, d1 = ev.y - xv.y, d2 = ev.z - xv.z, d3 = ev.w - xv.w;
  o.x = xv.x + d0; o.y = xv.y + d1; o.z = xv.z + d2; o.w = xv.w + d3;
  double s = (double)d0 * d0 + (double)d1 * d1 + (double)d2 * d2 + (double)d3 * d3;
  *(float4*)(out_qst + (size_t)base) = o;

  for (int m = 32; m; m >>= 1) s += __shfl_xor(s, m);
  __shared__ double wsum[4];
  int lane = threadIdx.x & 63, w = threadIdx.x >> 6;
  if (lane == 0) wsum[w] = s;
  __syncthreads();
  if (threadIdx.x == 0)
    partials[blockIdx.x] = (wsum[0] + wsum[1]) + (wsum[2] + wsum[3]);
}

__global__ void vq_zero(unsigned* counts) {
  int i = blockIdx.x * 256 + threadIdx.x;
  if (i < K_EMB) counts[i] = 0u;
}

__global__ void vq_hist(const int* __restrict__ idx, unsigned* __restrict__ counts) {
  int i = blockIdx.x * 256 + threadIdx.x;
  if (i < N_ROWS) atomicAdd(&counts[idx[i]], 1u);
}

__global__ __launch_bounds__(256) void vq_scalars(const double* __restrict__ partials,
                                                  const unsigned* __restrict__ counts,
                                                  float* __restrict__ out_loss,
                                                  float* __restrict__ out_perp) {
  __shared__ double red[256];
  int t = threadIdx.x;
  double s = 0.0;
  for (int i = t; i < 8192; i += 256) s += partials[i];
  red[t] = s;
  __syncthreads();
  for (int o = 128; o; o >>= 1) { if (t < o) red[t] += red[t + o]; __syncthreads(); }
  double mse = red[0] / (double)((size_t)N_ROWS * DIM);
  __syncthreads();

  double p = 0.0;
  for (int i = t; i < K_EMB; i += 256) {
    double pr = (double)counts[i] / (double)N_ROWS;
    p += pr * log(pr + 1e-10);
  }
  red[t] = p;
  __syncthreads();
  for (int o = 128; o; o >>= 1) { if (t < o) red[t] += red[t + o]; __syncthreads(); }
  if (t == 0) {
    float m = (float)mse;
    out_loss[0] = m + 0.25f * m;
    out_perp[0] = (float)exp(-red[0]);
  }
}

extern "C" void kernel_launch(void* const* d_in, const int* in_sizes, int n_in,
                              void* d_out, int out_size, void* d_ws, size_t ws_size,
                              hipStream_t stream) {
  const float* X = (const float*)d_in[0];   // [32768, 256]
  const float* E = (const float*)d_in[1];   // [8192, 256]
  float* out  = (float*)d_out;
  float* qst  = out;
  float* loss = out + 8388608;
  float* perp = out + 8388609;
  float* idxf = out + 8388610;

  // ws layout (bytes) — same as R5:
  //       0: A        f32[32768]
  //  131072: C        f32[8192]
  //  163840: idx      i32[32768]
  //  294912: hist     u32[8192]
  //  327680: partials f64[8192]
  //  393216: gcnt     u32[32768]
  //  524288: glist    i32[32768*24]  (3145728 B)
  // 3670016: Eb       bf16[8192*256] (4194304 B)  -> total 7864320 B
  float*    A        = (float*)d_ws;
  float*    C        = (float*)((char*)d_ws + 131072);
  int*      idx      = (int*)((char*)d_ws + 163840);
  unsigned* hist     = (unsigned*)((char*)d_ws + 294912);
  double*   partials = (double*)((char*)d_ws + 327680);
  unsigned* gcnt     = (unsigned*)((char*)d_ws + 393216);
  int*      glist    = (int*)((char*)d_ws + 524288);
  uint4*    Eb       = (uint4*)((char*)d_ws + 3670016);

  vq_zero  <<<32,  256, 0, stream>>>(hist);
  vq_sumsq <<<256, 256, 0, stream>>>(X, A, N_ROWS);
  vq_sumsq <<<64,  256, 0, stream>>>(E, C, K_EMB);

  if (ws_size >= 7864320) {
    vq_cvt_frag   <<<1024, 256, 0, stream>>>(E, Eb);
    vq_mfma_cand2 <<<256,  512, 0, stream>>>(X, Eb, A, C, gcnt, glist);
    vq_recheck    <<<8192, 256, 0, stream>>>(X, E, A, C, gcnt, glist, idx, idxf);
  } else {
    vq_argmin     <<<512,  256, 0, stream>>>(X, E, A, C, idx, idxf);
  }

  vq_quant  <<<8192, 256, 0, stream>>>(X, E, idx, qst, partials);
  vq_hist   <<<128,  256, 0, stream>>>(idx, hist);
  vq_scalars<<<1,    256, 0, stream>>>(partials, hist, loss, perp);
}